// Round 15
// baseline (682.707 us; speedup 1.0000x reference)
//
#include <hip/hip_runtime.h>
#include <stdint.h>
#include <math.h>

#define TT 516
#define BB 16
#define DD 512
#define LL 512
#define NN 512
#define HH 8
#define DHD 64
#define DFFN 2048
#define PP 336
#define MM 512
#define KNN 10
#define BT (BB*TT)      /* 8256 */
#define PN (PP*NN)      /* 172032 */
#define SKC 32          /* sims k-chunks */
#define SCHUNK (PN/SKC) /* 5376 */
#define SSTG (SCHUNK/256) /* 21 stages */
#define VSTR 528        /* transposed-V row stride (uint16 elems) */

using f32x4 = __attribute__((ext_vector_type(4))) float;
using f16x8 = __attribute__((ext_vector_type(8))) _Float16;
using u16x8 = __attribute__((ext_vector_type(8))) unsigned short;

__device__ __forceinline__ float gelu_tanh(float x){
    float x3 = x*x*x;
    return 0.5f*x*(1.0f + tanhf(0.7978845608028654f*(x + 0.044715f*x3)));
}

__device__ __forceinline__ uint16_t f2h(float x){
    _Float16 h = (_Float16)x;
    return __builtin_bit_cast(uint16_t, h);
}

__device__ __forceinline__ float h2f(uint16_t u){
    return (float)__builtin_bit_cast(_Float16, u);
}

__device__ __forceinline__ void gl16(const uint16_t* g, uint16_t* l){
    __builtin_amdgcn_global_load_lds(
        (const __attribute__((address_space(1))) unsigned int*)(const void*)g,
        (__attribute__((address_space(3))) unsigned int*)(void*)l, 16, 0, 0);
}

__device__ __forceinline__ f16x8 ldh8(const uint16_t* p){
    return __builtin_bit_cast(f16x8, *(const u16x8*)p);
}

#define EPI_F32   1
#define EPI_H16   2
#define EPI_GELU  4
#define EPI_PREDT 8
#define EPI_QKV   16

// ---------------------------------------------------------------------------
// Unified fp16 single-pass MFMA GEMM: BMxBN tile, BK=64.
// BM in {128,256}, BN in {64,128}. 4 waves as 2x2; per-wave M=BM/2, N=BN/2.
// ---------------------------------------------------------------------------
template<int BM, int BN, int FLAGS>
__global__ __launch_bounds__(256, 4)
void ggemm(const uint16_t* __restrict__ Ah, const uint16_t* __restrict__ Bh,
           const float* __restrict__ bias, float* __restrict__ Cf,
           uint16_t* __restrict__ Cb, uint16_t* __restrict__ Xkh,
           uint16_t* __restrict__ Xvh, int Msz, int Nsz, int Ksz)
{
    constexpr int FM = BM/32;            // fragment rows per wave; also A groups/wave
    constexpr int FN = BN/32;            // fragment cols per wave; also B groups/wave
    __shared__ uint16_t As0[BM*64];
    __shared__ uint16_t Bs0[BN*64];

    const int tid  = threadIdx.x;
    const int lane = tid & 63;
    const int wu   = __builtin_amdgcn_readfirstlane(tid >> 6);
    const int wm   = wu >> 1, wn = wu & 1;
    const int m0   = blockIdx.y * BM;
    const int n0   = blockIdx.x * BN;

    const int sr8 = lane >> 3;
    const int skw = (((lane & 7) ^ sr8) * 8);

    int rA[FM], rB[FN];
#pragma unroll
    for (int i=0;i<FM;i++){
        int r = m0 + (wu*FM + i)*8 + sr8;
        rA[i] = (r > Msz-1) ? Msz-1 : r;
    }
#pragma unroll
    for (int i=0;i<FN;i++){
        int r = n0 + (wu*FN + i)*8 + sr8;
        rB[i] = (r > Nsz-1) ? Nsz-1 : r;
    }

    f32x4 acc[FM][FN];
#pragma unroll
    for (int i=0;i<FM;i++)
#pragma unroll
        for (int j=0;j<FN;j++) acc[i][j] = (f32x4){0.f,0.f,0.f,0.f};

    const int lc16 = lane & 15;
    const int kgrp = lane >> 4;

    for (int kt = 0; kt < Ksz; kt += 64){
#pragma unroll
        for (int i=0;i<FM;i++)
            gl16(Ah + (size_t)rA[i]*Ksz + kt + skw, &As0[(wu*FM + i)*512]);
#pragma unroll
        for (int i=0;i<FN;i++)
            gl16(Bh + (size_t)rB[i]*Ksz + kt + skw, &Bs0[(wu*FN + i)*512]);
        __syncthreads();

#pragma unroll
        for (int ks=0; ks<2; ks++){
            f16x8 ah[FM];
#pragma unroll
            for (int fm=0; fm<FM; fm++){
                const int r   = wm*(BM/2) + fm*16 + lc16;
                const int off = r*64 + (((ks*4 + kgrp) ^ (r & 7))*8);
                ah[fm] = ldh8(&As0[off]);
            }
#pragma unroll
            for (int fn=0; fn<FN; fn++){
                const int rb   = wn*(BN/2) + fn*16 + lc16;
                const int offb = rb*64 + (((ks*4 + kgrp) ^ (rb & 7))*8);
                f16x8 bh = ldh8(&Bs0[offb]);
#pragma unroll
                for (int fm=0; fm<FM; fm++)
                    acc[fm][fn] = __builtin_amdgcn_mfma_f32_16x16x32_f16(ah[fm], bh, acc[fm][fn], 0,0,0);
            }
        }
        __syncthreads();
    }

    const int lr4 = (lane >> 4) * 4;
#pragma unroll
    for (int fm=0; fm<FM; fm++){
        const int rbase = m0 + wm*(BM/2) + fm*16 + lr4;
#pragma unroll
        for (int fn=0; fn<FN; fn++){
            const int col = n0 + wn*(BN/2) + fn*16 + lc16;
            f32x4 v = acc[fm][fn];
            if (FLAGS & EPI_QKV){
                const int g   = col >> 9;
                const int cc2 = col & 511;
                const int hh2 = cc2 >> 6, dd2 = cc2 & 63;
                const float bcol = bias[col];
#pragma unroll
                for (int r=0;r<4;r++){
                    int row = rbase + r;
                    if (row < Msz){
                        float x = v[r] + bcol;
                        int b2 = row / TT, t2 = row - b2*TT;
                        int bh2 = b2*HH + hh2;
                        if (g == 0){
                            size_t o = ((size_t)bh2*TT + t2)*64 + dd2;
                            Cb[o] = f2h(x * 0.125f);
                        } else if (g == 1){
                            size_t o = ((size_t)bh2*TT + t2)*64 + dd2;
                            Xkh[o] = f2h(x);
                        } else {
                            size_t o = ((size_t)bh2*64 + dd2)*VSTR + t2;
                            Xvh[o] = f2h(x);
                        }
                    }
                }
            } else if (FLAGS & EPI_PREDT){
#pragma unroll
                for (int r=0;r<4;r++){
                    int row = rbase + r;
                    if (row < Msz && col < PP){
                        int b = row / TT, t = row - b*TT;
                        if (t < NN)
                            Cf[((size_t)b*PP + col)*NN + t] = v[r] + bias[col];
                    }
                }
            } else {
                const float bcol = bias[col];
#pragma unroll
                for (int r=0;r<4;r++){
                    int row = rbase + r;
                    if (row < Msz){
                        float x = v[r] + bcol;
                        if (FLAGS & EPI_GELU) x = gelu_tanh(x);
                        if (FLAGS & EPI_F32) Cf[(size_t)row*Nsz + col] = x;
                        if (FLAGS & EPI_H16) Cb[(size_t)row*Nsz + col] = f2h(x);
                    }
                }
            }
        }
    }
}

// ---------------------------------------------------------------------------
// tok transpose -> fp16 single plane (unchanged)
// ---------------------------------------------------------------------------
__global__ __launch_bounds__(256)
void tok_k(const float* __restrict__ xe, const float* __restrict__ xm,
           uint16_t* __restrict__ th)
{
    const int b = blockIdx.z;
    const int t0 = blockIdx.x*32, l0 = blockIdx.y*32;
    __shared__ float tile[32][33];
    const int i = threadIdx.x >> 3;
    const int j4 = (threadIdx.x & 7) * 4;
#pragma unroll
    for (int c=0;c<4;c++){
        int t = t0 + j4 + c;
        float v = 0.0f;
        if (t < 512)      v = xe[((size_t)b*LL + l0+i)*NN + t];
        else if (t < 516) v = xm[((size_t)b*LL + l0+i)*4 + (t-512)];
        tile[i][j4+c] = v;
    }
    __syncthreads();
    int t = t0 + i;
    if (t < TT){
#pragma unroll
        for (int c=0;c<4;c++){
            size_t idx = ((size_t)b*TT + t)*512 + l0 + j4 + c;
            th[idx] = f2h(tile[j4+c][i]);
        }
    }
}

// ---------------------------------------------------------------------------
// ALL weight transposes in one launch, fp16 single plane (unchanged)
// ---------------------------------------------------------------------------
struct WtrDesc {
    const float* src; uint16_t* dh;
    int Ksz, Nsz, ntx, nty; size_t zstride; int base;
};
struct WtrTab { WtrDesc d[8]; };

__global__ __launch_bounds__(256)
void wtrall_k(WtrTab tab)
{
    const int bid = blockIdx.x;
    int e = 0;
#pragma unroll
    for (int i=1;i<8;i++) if (bid >= tab.d[i].base) e = i;
    const float* src = tab.d[e].src;
    uint16_t* dh = tab.d[e].dh;
    const int Ksz = tab.d[e].Ksz, Nsz = tab.d[e].Nsz;
    const int ntx = tab.d[e].ntx, nty = tab.d[e].nty;
    const size_t zs = tab.d[e].zstride;
    int local = bid - tab.d[e].base;
    const int tilesper = ntx*nty;
    const int z = local / tilesper;
    local -= z*tilesper;
    const int tyi = local / ntx;
    const int txi = local - tyi*ntx;
    src += (size_t)z*Ksz*Nsz; dh += (size_t)z*zs;
    const int kt = tyi*32, nt = txi*32;

    __shared__ float tile[32][33];
    const int i = threadIdx.x >> 3;
    const int j4 = (threadIdx.x & 7) * 4;
#pragma unroll
    for (int c=0;c<4;c++){
        int n = nt + j4 + c;
        tile[i][j4+c] = (n < Nsz) ? src[(size_t)(kt+i)*Nsz + n] : 0.0f;
    }
    __syncthreads();
    int n = nt + i;
    if (n < Nsz){
#pragma unroll
        for (int c=0;c<4;c++)
            dh[(size_t)n*Ksz + kt + j4 + c] = f2h(tile[j4+c][i]);
    }
}

__global__ void catb_k(const float* __restrict__ bq, const float* __restrict__ bk,
                       const float* __restrict__ bv, float* __restrict__ dst){
    int j = blockIdx.x*256 + threadIdx.x;
    if (j >= 3072) return;
    int layer = j / 1536, r = j - layer*1536;
    float v;
    if (r < 512)       v = bq[layer*512 + r];
    else if (r < 1024) v = bk[layer*512 + r - 512];
    else               v = bv[layer*512 + r - 1024];
    dst[j] = v;
}

// ---------------------------------------------------------------------------
// MFMA flash attention, fp16 (unchanged)
// ---------------------------------------------------------------------------
__global__ __launch_bounds__(256, 4)
void attnm_k(const uint16_t* __restrict__ qs, const uint16_t* __restrict__ ks,
             const uint16_t* __restrict__ vts, uint16_t* __restrict__ oh)
{
    const int qt = blockIdx.x;
    const int h  = blockIdx.y;
    const int b  = blockIdx.z;
    const int bh = b*HH + h;
    const int q0 = qt*64;
    const int tid  = threadIdx.x;
    const int lane = tid & 63;
    const int wu   = __builtin_amdgcn_readfirstlane(tid >> 6);
    const int mrow = lane & 15;
    const int kgrp = lane >> 4;

    __shared__ uint16_t Khs[4096];
    __shared__ uint16_t Vhs[4096];
    __shared__ uint16_t Phs[4096];

    int tq = q0 + wu*16 + mrow; if (tq > TT-1) tq = TT-1;
    const uint16_t* qbase = qs + ((size_t)bh*TT + tq)*64 + kgrp*8;
    f16x8 qfh[2];
    qfh[0] = ldh8(qbase);      qfh[1] = ldh8(qbase + 32);

    const int srw = lane >> 3;
    const int sg  = lane & 7;

    f32x4 oacc[4];
#pragma unroll
    for (int f=0;f<4;f++) oacc[f] = (f32x4){0.f,0.f,0.f,0.f};
    float m_r[4] = {-1e30f,-1e30f,-1e30f,-1e30f};
    float l_r[4] = {0.f,0.f,0.f,0.f};

    for (int st=0; st<9; ++st){
        const int s0 = st*64;
        __syncthreads();
#pragma unroll
        for (int c=0;c<2;c++){
            const int r   = wu*16 + c*8 + srw;
            const int gsl = sg ^ (r & 7);
            int sk = s0 + r; if (sk > TT-1) sk = TT-1;
            const uint16_t* ksh_ = ks  + ((size_t)bh*TT + sk)*64 + gsl*8;
            int cb = s0 + gsl*8; if (cb > VSTR-8) cb = VSTR-8;
            const uint16_t* vsh_ = vts + ((size_t)bh*64 + r)*VSTR + cb;
            gl16(ksh_, &Khs[(wu*16 + c*8)*64]);
            gl16(vsh_, &Vhs[(wu*16 + c*8)*64]);
        }
        __syncthreads();

        f32x4 sacc[4];
#pragma unroll
        for (int f=0;f<4;f++) sacc[f] = (f32x4){0.f,0.f,0.f,0.f};
#pragma unroll
        for (int ks2=0; ks2<2; ks2++){
#pragma unroll
            for (int f=0; f<4; f++){
                const int sr = f*16 + mrow;
                const int sl = ((ks2*4 + kgrp) ^ (sr & 7))*8;
                f16x8 kbh = ldh8(&Khs[sr*64 + sl]);
                sacc[f] = __builtin_amdgcn_mfma_f32_16x16x32_f16(qfh[ks2], kbh, sacc[f], 0,0,0);
            }
        }

        float alpha[4];
#pragma unroll
        for (int r=0;r<4;r++){
            float mx = -1e30f;
#pragma unroll
            for (int f=0;f<4;f++){
                float sv = sacc[f][r];
                if (s0 + f*16 + mrow >= TT) sv = -1e30f;
                sacc[f][r] = sv;
                mx = fmaxf(mx, sv);
            }
#pragma unroll
            for (int msk=1; msk<16; msk<<=1) mx = fmaxf(mx, __shfl_xor(mx, msk));
            float mn = fmaxf(m_r[r], mx);
            alpha[r] = __expf(m_r[r] - mn);
            m_r[r] = mn;
            float rs = 0.0f;
#pragma unroll
            for (int f=0;f<4;f++){
                float e = __expf(sacc[f][r] - mn);
                sacc[f][r] = e;
                rs += e;
            }
#pragma unroll
            for (int msk=1; msk<16; msk<<=1) rs += __shfl_xor(rs, msk);
            l_r[r] = l_r[r]*alpha[r] + rs;
#pragma unroll
            for (int f=0;f<4;f++) oacc[f][r] *= alpha[r];
        }

#pragma unroll
        for (int r=0;r<4;r++){
            const int tr = wu*16 + kgrp*4 + r;
#pragma unroll
            for (int f=0;f<4;f++){
                const int c = f*16 + mrow;
                const int idx = tr*64 + ((c>>3) ^ (tr&7))*8 + (c&7);
                Phs[idx] = f2h(sacc[f][r]);
            }
        }

#pragma unroll
        for (int ks2=0; ks2<2; ks2++){
            const int trr = wu*16 + mrow;
            const int psl = ((ks2*4 + kgrp) ^ (trr & 7))*8;
            f16x8 pah = ldh8(&Phs[trr*64 + psl]);
#pragma unroll
            for (int f=0; f<4; f++){
                const int dr = f*16 + mrow;
                const int vsl = ((ks2*4 + kgrp) ^ (dr & 7))*8;
                f16x8 vbh = ldh8(&Vhs[dr*64 + vsl]);
                oacc[f] = __builtin_amdgcn_mfma_f32_16x16x32_f16(pah, vbh, oacc[f], 0,0,0);
            }
        }
    }

#pragma unroll
    for (int r=0;r<4;r++){
        const int t = q0 + wu*16 + kgrp*4 + r;
        if (t < TT){
            const float inv = 1.0f / l_r[r];
#pragma unroll
            for (int f=0;f<4;f++){
                const int d = f*16 + mrow;
                size_t o = ((size_t)(b*TT + t))*DD + h*DHD + d;
                oh[o] = f2h(oacc[f][r]*inv);
            }
        }
    }
}

// ---------------------------------------------------------------------------
// Residual + LayerNorm: all-fp16 I/O (fp32 math), wave-per-row (unchanged)
// ---------------------------------------------------------------------------
__global__ __launch_bounds__(256)
void ln_k(const uint16_t* __restrict__ src, const uint16_t* __restrict__ res,
          const float* __restrict__ w, const float* __restrict__ bia,
          uint16_t* __restrict__ dst)
{
    const int r    = blockIdx.x*4 + (threadIdx.x >> 6);
    const int lane = threadIdx.x & 63;
    const int c0   = lane*8;
    const size_t off = (size_t)r*DD + c0;

    u16x8 xs = *(const u16x8*)(src + off);
    float x[8];
#pragma unroll
    for (int i=0;i<8;i++) x[i] = h2f(xs[i]);
    if (res){
        u16x8 rs = *(const u16x8*)(res + off);
#pragma unroll
        for (int i=0;i<8;i++) x[i] += h2f(rs[i]);
    }
    float s = 0.f, sq = 0.f;
#pragma unroll
    for (int i=0;i<8;i++){ s += x[i]; sq = fmaf(x[i], x[i], sq); }
#pragma unroll
    for (int msk=1; msk<64; msk<<=1){
        s  += __shfl_xor(s,  msk);
        sq += __shfl_xor(sq, msk);
    }
    float mu  = s * (1.0f/512.0f);
    float var = sq * (1.0f/512.0f) - mu*mu;
    float rsd = rsqrtf(var + 1e-5f);

    float4 w0 = *(const float4*)(w + c0);
    float4 w1 = *(const float4*)(w + c0 + 4);
    float4 b0 = *(const float4*)(bia + c0);
    float4 b1 = *(const float4*)(bia + c0 + 4);
    float wv[8] = {w0.x,w0.y,w0.z,w0.w,w1.x,w1.y,w1.z,w1.w};
    float bv[8] = {b0.x,b0.y,b0.z,b0.w,b1.x,b1.y,b1.z,b1.w};

    u16x8 vh;
#pragma unroll
    for (int i=0;i<8;i++) vh[i] = f2h((x[i]-mu)*rsd*wv[i] + bv[i]);
    *(u16x8*)(dst + off) = vh;
}

// ---------------------------------------------------------------------------
// sims v4 (unchanged, fp32)
// ---------------------------------------------------------------------------
__global__ __launch_bounds__(256, 4)
void sims_k(const float* __restrict__ pred, const float* __restrict__ bank,
            float* __restrict__ dotp, float* __restrict__ nrmp)
{
    const int jt = blockIdx.x, kt = blockIdx.y;
    const int tid  = threadIdx.x;
    const int qq    = tid & 7;
    const int slice = tid >> 3;
    const int sb    = slice*8;
    const int srow  = tid >> 4;
    const int tau   = tid & 15;

    __shared__ float BS[16*264];

    const int jr = jt*16 + srow;
    const float* bsrc = (jr < MM) ? (bank + (size_t)jr*PN)
                                  : (pred + (size_t)(jr - MM)*PN);
    bsrc += (size_t)kt*SCHUNK + tau*4;
    const float* p0 = pred + (size_t)qq*PN      + (size_t)kt*SCHUNK + sb;
    const float* p1 = pred + (size_t)(qq+8)*PN  + (size_t)kt*SCHUNK + sb;

    float acc0[16], acc1[16];
#pragma unroll
    for (int j=0;j<16;j++){ acc0[j] = 0.0f; acc1[j] = 0.0f; }
    float nr = 0.0f;

    float4 blv[4], pr0[2], pr1[2];
#pragma unroll
    for (int c=0;c<4;c++) blv[c] = *(const float4*)(bsrc + c*64);
    pr0[0] = *(const float4*)(p0); pr0[1] = *(const float4*)(p0 + 4);
    pr1[0] = *(const float4*)(p1); pr1[1] = *(const float4*)(p1 + 4);
    bsrc += 256; p0 += 256; p1 += 256;

    for (int st=0; st<SSTG; ++st){
#pragma unroll
        for (int c=0;c<4;c++){
            *(float4*)&BS[srow*264 + tau*4 + c*64] = blv[c];
            nr = fmaf(blv[c].x, blv[c].x, nr);
            nr = fmaf(blv[c].y, blv[c].y, nr);
            nr = fmaf(blv[c].z, blv[c].z, nr);
            nr = fmaf(blv[c].w, blv[c].w, nr);
        }
        float4 cp0[2] = {pr0[0], pr0[1]};
        float4 cp1[2] = {pr1[0], pr1[1]};
        if (st + 1 < SSTG){
#pragma unroll
            for (int c=0;c<4;c++) blv[c] = *(const float4*)(bsrc + c*64);
            pr0[0] = *(const float4*)(p0); pr0[1] = *(const float4*)(p0 + 4);
            pr1[0] = *(const float4*)(p1); pr1[1] = *(const float4*)(p1 + 4);
            bsrc += 256; p0 += 256; p1 += 256;
        }
        __syncthreads();
#pragma unroll
        for (int j=0;j<16;j++){
            float4 b0 = *(const float4*)&BS[j*264 + sb];
            float4 b1 = *(const float4*)&BS[j*264 + sb + 4];
            float a0 = acc0[j], a1 = acc1[j];
            a0 = fmaf(b0.x, cp0[0].x, a0); a0 = fmaf(b0.y, cp0[0].y, a0);
            a0 = fmaf(b0.z, cp0[0].z, a0); a0 = fmaf(b0.w, cp0[0].w, a0);
            a0 = fmaf(b1.x, cp0[1].x, a0); a0 = fmaf(b1.y, cp0[1].y, a0);
            a0 = fmaf(b1.z, cp0[1].z, a0); a0 = fmaf(b1.w, cp0[1].w, a0);
            a1 = fmaf(b0.x, cp1[0].x, a1); a1 = fmaf(b0.y, cp1[0].y, a1);
            a1 = fmaf(b0.z, cp1[0].z, a1); a1 = fmaf(b0.w, cp1[0].w, a1);
            a1 = fmaf(b1.x, cp1[1].x, a1); a1 = fmaf(b1.y, cp1[1].y, a1);
            a1 = fmaf(b1.z, cp1[1].z, a1); a1 = fmaf(b1.w, cp1[1].w, a1);
            acc0[j] = a0; acc1[j] = a1;
        }
        __syncthreads();
    }

#pragma unroll
    for (int m=8; m<64; m<<=1){
#pragma unroll
        for (int j=0;j<16;j++){
            acc0[j] += __shfl_xor(acc0[j], m);
            acc1[j] += __shfl_xor(acc1[j], m);
        }
    }
#pragma unroll
    for (int m=1;m<16;m<<=1) nr += __shfl_xor(nr, m);

    __syncthreads();
    float* RED = BS;
    const int wu2  = tid >> 6;
    const int lane = tid & 63;
    if (lane < 8){
#pragma unroll
        for (int j=0;j<16;j++){
            RED[(wu2*16 + j)*16 + lane]     = acc0[j];
            RED[(wu2*16 + j)*16 + lane + 8] = acc1[j];
        }
    }
    __syncthreads();
    const int j2 = tid >> 4, q2 = tid & 15;
    float s = RED[(0*16 + j2)*16 + q2] + RED[(1*16 + j2)*16 + q2]
            + RED[(2*16 + j2)*16 + q2] + RED[(3*16 + j2)*16 + q2];
    dotp[((size_t)kt*528 + jt*16 + j2)*16 + q2] = s;
    if (tau == 0) nrmp[kt*528 + jt*16 + srow] = nr;
}

// ---------------------------------------------------------------------------
// Fused sims tail (unchanged)
// ---------------------------------------------------------------------------
__global__ __launch_bounds__(256)
void simstail_k(const float* __restrict__ dotp, const float* __restrict__ nrmp,
                int* __restrict__ idx)
{
    const int q   = blockIdx.x;
    const int tid = threadIdx.x;
    __shared__ float invn[528];
    __shared__ float vals[528];

    for (int j=tid; j<528; j+=256){
        float s = 0.0f;
        for (int kt=0; kt<SKC; kt++) s += nrmp[kt*528 + j];
        invn[j] = 1.0f/(sqrtf(s) + 1e-8f);
    }
    __syncthreads();
    const float invq = invn[MM + q];
    for (int j=tid; j<528; j+=256){
        float s = 0.0f;
        for (int kt=0; kt<SKC; kt++) s += dotp[((size_t)kt*528 + j)*16 + q];
        vals[j] = s * invn[j] * invq;
    }
    __syncthreads();
    if (tid < 64){
        const int lane = tid;
        for (int kk=0; kk<KNN; kk++){
            float bv = -3.0e38f; int bi = 1<<30;
            for (int j=lane; j<528; j+=64){
                float v2 = vals[j];
                if (v2 > bv || (v2 == bv && j < bi)){ bv = v2; bi = j; }
            }
#pragma unroll
            for (int msk=1; msk<64; msk<<=1){
                float ov = __shfl_xor(bv, msk);
                int   oi = __shfl_xor(bi, msk);
                if (ov > bv || (ov == bv && oi < bi)){ bv = ov; bi = oi; }
            }
            if (lane == 0){
                idx[q*KNN + kk] = bi;
                vals[bi] = -3.0e38f;
            }
        }
    }
}

__global__ __launch_bounds__(256)
void fuse_k(const float* __restrict__ pred, const float* __restrict__ bank,
            const int* __restrict__ idx, float* __restrict__ out){
    int u = blockIdx.x*256 + threadIdx.x;
    int b = u / (PN/4);
    int e = (u - b*(PN/4)) * 4;
    int id[KNN];
#pragma unroll
    for (int k2=0;k2<KNN;k2++) id[k2] = idx[b*KNN + k2];
    float4 pv = *(const float4*)(pred + (size_t)b*PN + e);
    float ax = 0.5f*pv.x, ay = 0.5f*pv.y, az = 0.5f*pv.z, aw = 0.5f*pv.w;
#pragma unroll
    for (int k2=0;k2<KNN;k2++){
        const float* rp = (id[k2] < MM) ? (bank + (size_t)id[k2]*PN)
                                        : (pred + (size_t)(id[k2]-MM)*PN);
        float4 rv = *(const float4*)(rp + e);
        ax = fmaf(0.05f, rv.x, ax); ay = fmaf(0.05f, rv.y, ay);
        az = fmaf(0.05f, rv.z, az); aw = fmaf(0.05f, rv.w, aw);
    }
    float4 ov; ov.x=ax; ov.y=ay; ov.z=az; ov.w=aw;
    *(float4*)(out + (size_t)b*PN + e) = ov;
}

// ---------------------------------------------------------------------------
extern "C" void kernel_launch(void* const* d_in, const int* in_sizes, int n_in,
                              void* d_out, int out_size, void* d_ws, size_t ws_size,
                              hipStream_t stream)
{
    (void)in_sizes; (void)n_in; (void)out_size; (void)ws_size;
    const float* x_enc  = (const float*)d_in[0];
    const float* x_mark = (const float*)d_in[1];
    const float* W_emb  = (const float*)d_in[4];
    const float* b_emb  = (const float*)d_in[5];
    const float* Wq  = (const float*)d_in[6];
    const float* Wk  = (const float*)d_in[7];
    const float* Wv  = (const float*)d_in[8];
    const float* Wo  = (const float*)d_in[9];
    const float* bq  = (const float*)d_in[10];
    const float* bk  = (const float*)d_in[11];
    const float* bv_ = (const float*)d_in[12];
    const float* bo  = (const float*)d_in[13];
    const float* ln1w = (const float*)d_in[14];
    const float* ln1b = (const float*)d_in[15];
    const float* ln2w = (const float*)d_in[16];
    const float* ln2b = (const float*)d_in[17];
    const float* Wff1 = (const float*)d_in[18];
    const float* bff1 = (const float*)d_in[19];
    const float* Wff2 = (const float*)d_in[20];
    const float* bff2 = (const float*)d_in[21];
    const float* lnfw = (const float*)d_in[22];
    const float* lnfb = (const float*)d_in[23];
    const float* Wproj = (const float*)d_in[24];
    const float* bproj = (const float*)d_in[25];
    const float* bank  = (const float*)d_in[26];
    float* out = (float*)d_out;

    char* pp = (char*)d_ws;
    auto a16 = [&](size_t elems)->uint16_t*{ uint16_t* r=(uint16_t*)pp; pp += ((elems*2 + 255)/256)*256; return r; };
    auto af  = [&](size_t elems)->float*  { float* r=(float*)pp;  pp += ((elems*4 + 255)/256)*256; return r; };

    uint16_t* wembT = a16(262144);
    uint16_t* wqkvT = a16((size_t)2*1536*512);
    uint16_t* woT   = a16((size_t)2*262144);
    uint16_t* wff1T = a16((size_t)2*2048*512);
    uint16_t* wff2T = a16((size_t)2*512*2048);
    uint16_t* wprjT = a16(172032);
    float*    bqkv  = af(3072);
    uint16_t* hb    = a16((size_t)BT*512);    // fp16 residual stream
    uint16_t* tok   = a16((size_t)BT*512);
    uint16_t* og16  = a16((size_t)BT*512);    // fp16 sublayer outputs
    uint16_t* qsh   = a16((size_t)128*TT*64);
    uint16_t* ksh   = a16((size_t)128*TT*64);
    uint16_t* vsh   = a16((size_t)128*64*VSTR + 4096);
    uint16_t* t1b   = a16((size_t)BT*512);
    uint16_t* midb  = qsh;   // FF1 out aliases qsh..t1b (all dead at FF1 time)
    float*    pred  = af((size_t)BB*PN);
    float*    dotp  = af((size_t)SKC*528*16);
    float*    nrmp  = af(SKC*528);
    int*      idxp  = (int*)af(256);

    dim3 blk(256);

    tok_k<<<dim3(17,16,BB), blk, 0, stream>>>(x_enc, x_mark, tok);

    WtrTab tab;
    tab.d[0] = { W_emb, wembT, 512, 512, 16, 16, 262144, 0 };
    tab.d[1] = { Wq, wqkvT,          512, 512, 16, 16, 786432, 256 };
    tab.d[2] = { Wk, wqkvT + 262144, 512, 512, 16, 16, 786432, 768 };
    tab.d[3] = { Wv, wqkvT + 524288, 512, 512, 16, 16, 786432, 1280 };
    tab.d[4] = { Wo, woT, 512, 512, 16, 16, 262144, 1792 };
    tab.d[5] = { Wff1, wff1T, 512, 2048, 64, 16, 1048576, 2304 };
    tab.d[6] = { Wff2, wff2T, 2048, 512, 16, 64, 1048576, 4352 };
    tab.d[7] = { Wproj, wprjT, 512, 336, 11, 16, 172032, 6400 };
    wtrall_k<<<dim3(6576), blk, 0, stream>>>(tab);
    catb_k<<<dim3(12), blk, 0, stream>>>(bq, bk, bv_, bqkv);

    // BN=64 family now BM=256 (33 M-tiles), barrier pairs halved per output
    ggemm<256, 64, EPI_H16><<<dim3(8,33), blk, 0, stream>>>(
        tok, wembT, b_emb, nullptr, hb, nullptr, nullptr, BT, 512, 512);

    for (int i=0;i<2;i++){
        ggemm<128, 128, EPI_QKV><<<dim3(12,65), blk, 0, stream>>>(
            hb, wqkvT + (size_t)i*786432, bqkv + i*1536,
            nullptr, qsh, ksh, vsh, BT, 1536, 512);
        attnm_k<<<dim3(9,HH,BB), blk, 0, stream>>>(qsh, ksh, vsh, t1b);
        ggemm<256, 64, EPI_H16><<<dim3(8,33), blk, 0, stream>>>(
            t1b, woT + (size_t)i*262144, bo + i*512, nullptr, og16,
            nullptr, nullptr, BT, 512, 512);
        ln_k<<<dim3(BT/4), blk, 0, stream>>>(hb, og16, ln1w + i*512, ln1b + i*512, hb);
        ggemm<128, 128, EPI_GELU|EPI_H16><<<dim3(16,65), blk, 0, stream>>>(
            hb, wff1T + (size_t)i*1048576, bff1 + i*DFFN,
            nullptr, midb, nullptr, nullptr, BT, DFFN, 512);
        ggemm<256, 64, EPI_H16><<<dim3(8,33), blk, 0, stream>>>(
            midb, wff2T + (size_t)i*1048576, bff2 + i*512, nullptr, og16,
            nullptr, nullptr, BT, 512, DFFN);
        ln_k<<<dim3(BT/4), blk, 0, stream>>>(hb, og16, ln2w + i*512, ln2b + i*512, hb);
    }

    ln_k<<<dim3(BT/4), blk, 0, stream>>>(hb, nullptr, lnfw, lnfb, hb);

    ggemm<256, 64, EPI_PREDT><<<dim3(6,33), blk, 0, stream>>>(
        hb, wprjT, bproj, pred, nullptr, nullptr, nullptr, BT, PP, 512);

    sims_k<<<dim3(33,SKC), blk, 0, stream>>>(pred, bank, dotp, nrmp);
    simstail_k<<<dim3(BB), blk, 0, stream>>>(dotp, nrmp, idxp);
    fuse_k<<<dim3((BB*PN/4)/256), blk, 0, stream>>>(pred, bank, idxp, out);
}

// Round 16
// 637.603 us; speedup vs baseline: 1.0707x; 1.0707x over previous
//
#include <hip/hip_runtime.h>
#include <stdint.h>
#include <math.h>

#define TT 516
#define BB 16
#define DD 512
#define LL 512
#define NN 512
#define HH 8
#define DHD 64
#define DFFN 2048
#define PP 336
#define MM 512
#define KNN 10
#define BT (BB*TT)      /* 8256 */
#define PN (PP*NN)      /* 172032 */
#define SKC 32          /* sims k-chunks */
#define SCHUNK (PN/SKC) /* 5376 */
#define SSTG (SCHUNK/256) /* 21 stages */
#define VSTR 528        /* transposed-V row stride (uint16 elems) */

using f32x4 = __attribute__((ext_vector_type(4))) float;
using f16x8 = __attribute__((ext_vector_type(8))) _Float16;
using u16x8 = __attribute__((ext_vector_type(8))) unsigned short;

__device__ __forceinline__ float gelu_tanh(float x){
    float x3 = x*x*x;
    return 0.5f*x*(1.0f + tanhf(0.7978845608028654f*(x + 0.044715f*x3)));
}

__device__ __forceinline__ uint16_t f2h(float x){
    _Float16 h = (_Float16)x;
    return __builtin_bit_cast(uint16_t, h);
}

__device__ __forceinline__ float h2f(uint16_t u){
    return (float)__builtin_bit_cast(_Float16, u);
}

__device__ __forceinline__ void gl16(const uint16_t* g, uint16_t* l){
    __builtin_amdgcn_global_load_lds(
        (const __attribute__((address_space(1))) unsigned int*)(const void*)g,
        (__attribute__((address_space(3))) unsigned int*)(void*)l, 16, 0, 0);
}

__device__ __forceinline__ f16x8 ldh8(const uint16_t* p){
    return __builtin_bit_cast(f16x8, *(const u16x8*)p);
}

#define EPI_F32   1
#define EPI_H16   2
#define EPI_GELU  4
#define EPI_PREDT 8
#define EPI_QKV   16

// ---------------------------------------------------------------------------
// Unified fp16 single-pass MFMA GEMM: 128xBN tile, BK=64. BN in {64,128}.
// (round-14 state; BM=256 variant regressed in round 15 — reverted)
// ---------------------------------------------------------------------------
template<int BN, int FLAGS>
__global__ __launch_bounds__(256, 4)
void ggemm(const uint16_t* __restrict__ Ah, const uint16_t* __restrict__ Bh,
           const float* __restrict__ bias, float* __restrict__ Cf,
           uint16_t* __restrict__ Cb, uint16_t* __restrict__ Xkh,
           uint16_t* __restrict__ Xvh, int Msz, int Nsz, int Ksz)
{
    constexpr int FN = BN/32;
    __shared__ uint16_t As0[8192];
    __shared__ uint16_t Bs0[BN*64];

    const int tid  = threadIdx.x;
    const int lane = tid & 63;
    const int wu   = __builtin_amdgcn_readfirstlane(tid >> 6);
    const int wm   = wu >> 1, wn = wu & 1;
    const int m0   = blockIdx.y * 128;
    const int n0   = blockIdx.x * BN;

    const int sr8 = lane >> 3;
    const int skw = (((lane & 7) ^ sr8) * 8);

    int rA[4], rB[FN];
#pragma unroll
    for (int i=0;i<4;i++){
        int r = m0 + (wu*4 + i)*8 + sr8;
        rA[i] = (r > Msz-1) ? Msz-1 : r;
    }
#pragma unroll
    for (int i=0;i<FN;i++){
        int r = n0 + (wu*FN + i)*8 + sr8;
        rB[i] = (r > Nsz-1) ? Nsz-1 : r;
    }

    f32x4 acc[4][FN];
#pragma unroll
    for (int i=0;i<4;i++)
#pragma unroll
        for (int j=0;j<FN;j++) acc[i][j] = (f32x4){0.f,0.f,0.f,0.f};

    const int lc16 = lane & 15;
    const int kgrp = lane >> 4;

    for (int kt = 0; kt < Ksz; kt += 64){
#pragma unroll
        for (int i=0;i<4;i++)
            gl16(Ah + (size_t)rA[i]*Ksz + kt + skw, &As0[(wu*4 + i)*512]);
#pragma unroll
        for (int i=0;i<FN;i++)
            gl16(Bh + (size_t)rB[i]*Ksz + kt + skw, &Bs0[(wu*FN + i)*512]);
        __syncthreads();

#pragma unroll
        for (int ks=0; ks<2; ks++){
            f16x8 ah[4];
#pragma unroll
            for (int fm=0; fm<4; fm++){
                const int r   = wm*64 + fm*16 + lc16;
                const int off = r*64 + (((ks*4 + kgrp) ^ (r & 7))*8);
                ah[fm] = ldh8(&As0[off]);
            }
#pragma unroll
            for (int fn=0; fn<FN; fn++){
                const int rb   = wn*(BN/2) + fn*16 + lc16;
                const int offb = rb*64 + (((ks*4 + kgrp) ^ (rb & 7))*8);
                f16x8 bh = ldh8(&Bs0[offb]);
#pragma unroll
                for (int fm=0; fm<4; fm++)
                    acc[fm][fn] = __builtin_amdgcn_mfma_f32_16x16x32_f16(ah[fm], bh, acc[fm][fn], 0,0,0);
            }
        }
        __syncthreads();
    }

    const int lr4 = (lane >> 4) * 4;
#pragma unroll
    for (int fm=0; fm<4; fm++){
        const int rbase = m0 + wm*64 + fm*16 + lr4;
#pragma unroll
        for (int fn=0; fn<FN; fn++){
            const int col = n0 + wn*(BN/2) + fn*16 + lc16;
            f32x4 v = acc[fm][fn];
            if (FLAGS & EPI_QKV){
                const int g   = col >> 9;
                const int cc2 = col & 511;
                const int hh2 = cc2 >> 6, dd2 = cc2 & 63;
                const float bcol = bias[col];
#pragma unroll
                for (int r=0;r<4;r++){
                    int row = rbase + r;
                    if (row < Msz){
                        float x = v[r] + bcol;
                        int b2 = row / TT, t2 = row - b2*TT;
                        int bh2 = b2*HH + hh2;
                        if (g == 0){
                            size_t o = ((size_t)bh2*TT + t2)*64 + dd2;
                            Cb[o] = f2h(x * 0.125f);
                        } else if (g == 1){
                            size_t o = ((size_t)bh2*TT + t2)*64 + dd2;
                            Xkh[o] = f2h(x);
                        } else {
                            size_t o = ((size_t)bh2*64 + dd2)*VSTR + t2;
                            Xvh[o] = f2h(x);
                        }
                    }
                }
            } else if (FLAGS & EPI_PREDT){
#pragma unroll
                for (int r=0;r<4;r++){
                    int row = rbase + r;
                    if (row < Msz && col < PP){
                        int b = row / TT, t = row - b*TT;
                        if (t < NN)
                            Cf[((size_t)b*PP + col)*NN + t] = v[r] + bias[col];
                    }
                }
            } else {
                const float bcol = bias[col];
#pragma unroll
                for (int r=0;r<4;r++){
                    int row = rbase + r;
                    if (row < Msz){
                        float x = v[r] + bcol;
                        if (FLAGS & EPI_GELU) x = gelu_tanh(x);
                        if (FLAGS & EPI_F32) Cf[(size_t)row*Nsz + col] = x;
                        if (FLAGS & EPI_H16) Cb[(size_t)row*Nsz + col] = f2h(x);
                    }
                }
            }
        }
    }
}

// ---------------------------------------------------------------------------
// tok transpose -> fp16 single plane
// ---------------------------------------------------------------------------
__global__ __launch_bounds__(256)
void tok_k(const float* __restrict__ xe, const float* __restrict__ xm,
           uint16_t* __restrict__ th)
{
    const int b = blockIdx.z;
    const int t0 = blockIdx.x*32, l0 = blockIdx.y*32;
    __shared__ float tile[32][33];
    const int i = threadIdx.x >> 3;
    const int j4 = (threadIdx.x & 7) * 4;
#pragma unroll
    for (int c=0;c<4;c++){
        int t = t0 + j4 + c;
        float v = 0.0f;
        if (t < 512)      v = xe[((size_t)b*LL + l0+i)*NN + t];
        else if (t < 516) v = xm[((size_t)b*LL + l0+i)*4 + (t-512)];
        tile[i][j4+c] = v;
    }
    __syncthreads();
    int t = t0 + i;
    if (t < TT){
#pragma unroll
        for (int c=0;c<4;c++){
            size_t idx = ((size_t)b*TT + t)*512 + l0 + j4 + c;
            th[idx] = f2h(tile[j4+c][i]);
        }
    }
}

// ---------------------------------------------------------------------------
// ALL weight transposes in one launch, fp16 single plane
// ---------------------------------------------------------------------------
struct WtrDesc {
    const float* src; uint16_t* dh;
    int Ksz, Nsz, ntx, nty; size_t zstride; int base;
};
struct WtrTab { WtrDesc d[8]; };

__global__ __launch_bounds__(256)
void wtrall_k(WtrTab tab)
{
    const int bid = blockIdx.x;
    int e = 0;
#pragma unroll
    for (int i=1;i<8;i++) if (bid >= tab.d[i].base) e = i;
    const float* src = tab.d[e].src;
    uint16_t* dh = tab.d[e].dh;
    const int Ksz = tab.d[e].Ksz, Nsz = tab.d[e].Nsz;
    const int ntx = tab.d[e].ntx, nty = tab.d[e].nty;
    const size_t zs = tab.d[e].zstride;
    int local = bid - tab.d[e].base;
    const int tilesper = ntx*nty;
    const int z = local / tilesper;
    local -= z*tilesper;
    const int tyi = local / ntx;
    const int txi = local - tyi*ntx;
    src += (size_t)z*Ksz*Nsz; dh += (size_t)z*zs;
    const int kt = tyi*32, nt = txi*32;

    __shared__ float tile[32][33];
    const int i = threadIdx.x >> 3;
    const int j4 = (threadIdx.x & 7) * 4;
#pragma unroll
    for (int c=0;c<4;c++){
        int n = nt + j4 + c;
        tile[i][j4+c] = (n < Nsz) ? src[(size_t)(kt+i)*Nsz + n] : 0.0f;
    }
    __syncthreads();
    int n = nt + i;
    if (n < Nsz){
#pragma unroll
        for (int c=0;c<4;c++)
            dh[(size_t)n*Ksz + kt + j4 + c] = f2h(tile[j4+c][i]);
    }
}

__global__ void catb_k(const float* __restrict__ bq, const float* __restrict__ bk,
                       const float* __restrict__ bv, float* __restrict__ dst){
    int j = blockIdx.x*256 + threadIdx.x;
    if (j >= 3072) return;
    int layer = j / 1536, r = j - layer*1536;
    float v;
    if (r < 512)       v = bq[layer*512 + r];
    else if (r < 1024) v = bk[layer*512 + r - 512];
    else               v = bv[layer*512 + r - 1024];
    dst[j] = v;
}

// ---------------------------------------------------------------------------
// MFMA flash attention, fp16
// ---------------------------------------------------------------------------
__global__ __launch_bounds__(256, 4)
void attnm_k(const uint16_t* __restrict__ qs, const uint16_t* __restrict__ ks,
             const uint16_t* __restrict__ vts, uint16_t* __restrict__ oh)
{
    const int qt = blockIdx.x;
    const int h  = blockIdx.y;
    const int b  = blockIdx.z;
    const int bh = b*HH + h;
    const int q0 = qt*64;
    const int tid  = threadIdx.x;
    const int lane = tid & 63;
    const int wu   = __builtin_amdgcn_readfirstlane(tid >> 6);
    const int mrow = lane & 15;
    const int kgrp = lane >> 4;

    __shared__ uint16_t Khs[4096];
    __shared__ uint16_t Vhs[4096];
    __shared__ uint16_t Phs[4096];

    int tq = q0 + wu*16 + mrow; if (tq > TT-1) tq = TT-1;
    const uint16_t* qbase = qs + ((size_t)bh*TT + tq)*64 + kgrp*8;
    f16x8 qfh[2];
    qfh[0] = ldh8(qbase);      qfh[1] = ldh8(qbase + 32);

    const int srw = lane >> 3;
    const int sg  = lane & 7;

    f32x4 oacc[4];
#pragma unroll
    for (int f=0;f<4;f++) oacc[f] = (f32x4){0.f,0.f,0.f,0.f};
    float m_r[4] = {-1e30f,-1e30f,-1e30f,-1e30f};
    float l_r[4] = {0.f,0.f,0.f,0.f};

    for (int st=0; st<9; ++st){
        const int s0 = st*64;
        __syncthreads();
#pragma unroll
        for (int c=0;c<2;c++){
            const int r   = wu*16 + c*8 + srw;
            const int gsl = sg ^ (r & 7);
            int sk = s0 + r; if (sk > TT-1) sk = TT-1;
            const uint16_t* ksh_ = ks  + ((size_t)bh*TT + sk)*64 + gsl*8;
            int cb = s0 + gsl*8; if (cb > VSTR-8) cb = VSTR-8;
            const uint16_t* vsh_ = vts + ((size_t)bh*64 + r)*VSTR + cb;
            gl16(ksh_, &Khs[(wu*16 + c*8)*64]);
            gl16(vsh_, &Vhs[(wu*16 + c*8)*64]);
        }
        __syncthreads();

        f32x4 sacc[4];
#pragma unroll
        for (int f=0;f<4;f++) sacc[f] = (f32x4){0.f,0.f,0.f,0.f};
#pragma unroll
        for (int ks2=0; ks2<2; ks2++){
#pragma unroll
            for (int f=0; f<4; f++){
                const int sr = f*16 + mrow;
                const int sl = ((ks2*4 + kgrp) ^ (sr & 7))*8;
                f16x8 kbh = ldh8(&Khs[sr*64 + sl]);
                sacc[f] = __builtin_amdgcn_mfma_f32_16x16x32_f16(qfh[ks2], kbh, sacc[f], 0,0,0);
            }
        }

        float alpha[4];
#pragma unroll
        for (int r=0;r<4;r++){
            float mx = -1e30f;
#pragma unroll
            for (int f=0;f<4;f++){
                float sv = sacc[f][r];
                if (s0 + f*16 + mrow >= TT) sv = -1e30f;
                sacc[f][r] = sv;
                mx = fmaxf(mx, sv);
            }
#pragma unroll
            for (int msk=1; msk<16; msk<<=1) mx = fmaxf(mx, __shfl_xor(mx, msk));
            float mn = fmaxf(m_r[r], mx);
            alpha[r] = __expf(m_r[r] - mn);
            m_r[r] = mn;
            float rs = 0.0f;
#pragma unroll
            for (int f=0;f<4;f++){
                float e = __expf(sacc[f][r] - mn);
                sacc[f][r] = e;
                rs += e;
            }
#pragma unroll
            for (int msk=1; msk<16; msk<<=1) rs += __shfl_xor(rs, msk);
            l_r[r] = l_r[r]*alpha[r] + rs;
#pragma unroll
            for (int f=0;f<4;f++) oacc[f][r] *= alpha[r];
        }

#pragma unroll
        for (int r=0;r<4;r++){
            const int tr = wu*16 + kgrp*4 + r;
#pragma unroll
            for (int f=0;f<4;f++){
                const int c = f*16 + mrow;
                const int idx = tr*64 + ((c>>3) ^ (tr&7))*8 + (c&7);
                Phs[idx] = f2h(sacc[f][r]);
            }
        }
        // same-wave DS ordering: reads below touch only rows this wave wrote

#pragma unroll
        for (int ks2=0; ks2<2; ks2++){
            const int trr = wu*16 + mrow;
            const int psl = ((ks2*4 + kgrp) ^ (trr & 7))*8;
            f16x8 pah = ldh8(&Phs[trr*64 + psl]);
#pragma unroll
            for (int f=0; f<4; f++){
                const int dr = f*16 + mrow;
                const int vsl = ((ks2*4 + kgrp) ^ (dr & 7))*8;
                f16x8 vbh = ldh8(&Vhs[dr*64 + vsl]);
                oacc[f] = __builtin_amdgcn_mfma_f32_16x16x32_f16(pah, vbh, oacc[f], 0,0,0);
            }
        }
    }

#pragma unroll
    for (int r=0;r<4;r++){
        const int t = q0 + wu*16 + kgrp*4 + r;
        if (t < TT){
            const float inv = 1.0f / l_r[r];
#pragma unroll
            for (int f=0;f<4;f++){
                const int d = f*16 + mrow;
                size_t o = ((size_t)(b*TT + t))*DD + h*DHD + d;
                oh[o] = f2h(oacc[f][r]*inv);
            }
        }
    }
}

// ---------------------------------------------------------------------------
// Residual + LayerNorm: all-fp16 I/O (fp32 math), wave-per-row, in-place.
// ---------------------------------------------------------------------------
__global__ __launch_bounds__(256)
void ln_k(const uint16_t* __restrict__ src, const uint16_t* __restrict__ res,
          const float* __restrict__ w, const float* __restrict__ bia,
          uint16_t* __restrict__ dst)
{
    const int r    = blockIdx.x*4 + (threadIdx.x >> 6);
    const int lane = threadIdx.x & 63;
    const int c0   = lane*8;
    const size_t off = (size_t)r*DD + c0;

    u16x8 xs = *(const u16x8*)(src + off);
    float x[8];
#pragma unroll
    for (int i=0;i<8;i++) x[i] = h2f(xs[i]);
    if (res){
        u16x8 rs = *(const u16x8*)(res + off);
#pragma unroll
        for (int i=0;i<8;i++) x[i] += h2f(rs[i]);
    }
    float s = 0.f, sq = 0.f;
#pragma unroll
    for (int i=0;i<8;i++){ s += x[i]; sq = fmaf(x[i], x[i], sq); }
#pragma unroll
    for (int msk=1; msk<64; msk<<=1){
        s  += __shfl_xor(s,  msk);
        sq += __shfl_xor(sq, msk);
    }
    float mu  = s * (1.0f/512.0f);
    float var = sq * (1.0f/512.0f) - mu*mu;
    float rsd = rsqrtf(var + 1e-5f);

    float4 w0 = *(const float4*)(w + c0);
    float4 w1 = *(const float4*)(w + c0 + 4);
    float4 b0 = *(const float4*)(bia + c0);
    float4 b1 = *(const float4*)(bia + c0 + 4);
    float wv[8] = {w0.x,w0.y,w0.z,w0.w,w1.x,w1.y,w1.z,w1.w};
    float bv[8] = {b0.x,b0.y,b0.z,b0.w,b1.x,b1.y,b1.z,b1.w};

    u16x8 vh;
#pragma unroll
    for (int i=0;i<8;i++) vh[i] = f2h((x[i]-mu)*rsd*wv[i] + bv[i]);
    *(u16x8*)(dst + off) = vh;
}

// ---------------------------------------------------------------------------
// sims v4 (unchanged, fp32)
// ---------------------------------------------------------------------------
__global__ __launch_bounds__(256, 4)
void sims_k(const float* __restrict__ pred, const float* __restrict__ bank,
            float* __restrict__ dotp, float* __restrict__ nrmp)
{
    const int jt = blockIdx.x, kt = blockIdx.y;
    const int tid  = threadIdx.x;
    const int qq    = tid & 7;
    const int slice = tid >> 3;
    const int sb    = slice*8;
    const int srow  = tid >> 4;
    const int tau   = tid & 15;

    __shared__ float BS[16*264];

    const int jr = jt*16 + srow;
    const float* bsrc = (jr < MM) ? (bank + (size_t)jr*PN)
                                  : (pred + (size_t)(jr - MM)*PN);
    bsrc += (size_t)kt*SCHUNK + tau*4;
    const float* p0 = pred + (size_t)qq*PN      + (size_t)kt*SCHUNK + sb;
    const float* p1 = pred + (size_t)(qq+8)*PN  + (size_t)kt*SCHUNK + sb;

    float acc0[16], acc1[16];
#pragma unroll
    for (int j=0;j<16;j++){ acc0[j] = 0.0f; acc1[j] = 0.0f; }
    float nr = 0.0f;

    float4 blv[4], pr0[2], pr1[2];
#pragma unroll
    for (int c=0;c<4;c++) blv[c] = *(const float4*)(bsrc + c*64);
    pr0[0] = *(const float4*)(p0); pr0[1] = *(const float4*)(p0 + 4);
    pr1[0] = *(const float4*)(p1); pr1[1] = *(const float4*)(p1 + 4);
    bsrc += 256; p0 += 256; p1 += 256;

    for (int st=0; st<SSTG; ++st){
#pragma unroll
        for (int c=0;c<4;c++){
            *(float4*)&BS[srow*264 + tau*4 + c*64] = blv[c];
            nr = fmaf(blv[c].x, blv[c].x, nr);
            nr = fmaf(blv[c].y, blv[c].y, nr);
            nr = fmaf(blv[c].z, blv[c].z, nr);
            nr = fmaf(blv[c].w, blv[c].w, nr);
        }
        float4 cp0[2] = {pr0[0], pr0[1]};
        float4 cp1[2] = {pr1[0], pr1[1]};
        if (st + 1 < SSTG){
#pragma unroll
            for (int c=0;c<4;c++) blv[c] = *(const float4*)(bsrc + c*64);
            pr0[0] = *(const float4*)(p0); pr0[1] = *(const float4*)(p0 + 4);
            pr1[0] = *(const float4*)(p1); pr1[1] = *(const float4*)(p1 + 4);
            bsrc += 256; p0 += 256; p1 += 256;
        }
        __syncthreads();
#pragma unroll
        for (int j=0;j<16;j++){
            float4 b0 = *(const float4*)&BS[j*264 + sb];
            float4 b1 = *(const float4*)&BS[j*264 + sb + 4];
            float a0 = acc0[j], a1 = acc1[j];
            a0 = fmaf(b0.x, cp0[0].x, a0); a0 = fmaf(b0.y, cp0[0].y, a0);
            a0 = fmaf(b0.z, cp0[0].z, a0); a0 = fmaf(b0.w, cp0[0].w, a0);
            a0 = fmaf(b1.x, cp0[1].x, a0); a0 = fmaf(b1.y, cp0[1].y, a0);
            a0 = fmaf(b1.z, cp0[1].z, a0); a0 = fmaf(b1.w, cp0[1].w, a0);
            a1 = fmaf(b0.x, cp1[0].x, a1); a1 = fmaf(b0.y, cp1[0].y, a1);
            a1 = fmaf(b0.z, cp1[0].z, a1); a1 = fmaf(b0.w, cp1[0].w, a1);
            a1 = fmaf(b1.x, cp1[1].x, a1); a1 = fmaf(b1.y, cp1[1].y, a1);
            a1 = fmaf(b1.z, cp1[1].z, a1); a1 = fmaf(b1.w, cp1[1].w, a1);
            acc0[j] = a0; acc1[j] = a1;
        }
        __syncthreads();
    }

#pragma unroll
    for (int m=8; m<64; m<<=1){
#pragma unroll
        for (int j=0;j<16;j++){
            acc0[j] += __shfl_xor(acc0[j], m);
            acc1[j] += __shfl_xor(acc1[j], m);
        }
    }
#pragma unroll
    for (int m=1;m<16;m<<=1) nr += __shfl_xor(nr, m);

    __syncthreads();
    float* RED = BS;
    const int wu2  = tid >> 6;
    const int lane = tid & 63;
    if (lane < 8){
#pragma unroll
        for (int j=0;j<16;j++){
            RED[(wu2*16 + j)*16 + lane]     = acc0[j];
            RED[(wu2*16 + j)*16 + lane + 8] = acc1[j];
        }
    }
    __syncthreads();
    const int j2 = tid >> 4, q2 = tid & 15;
    float s = RED[(0*16 + j2)*16 + q2] + RED[(1*16 + j2)*16 + q2]
            + RED[(2*16 + j2)*16 + q2] + RED[(3*16 + j2)*16 + q2];
    dotp[((size_t)kt*528 + jt*16 + j2)*16 + q2] = s;
    if (tau == 0) nrmp[kt*528 + jt*16 + srow] = nr;
}

// ---------------------------------------------------------------------------
// Fused sims tail (unchanged)
// ---------------------------------------------------------------------------
__global__ __launch_bounds__(256)
void simstail_k(const float* __restrict__ dotp, const float* __restrict__ nrmp,
                int* __restrict__ idx)
{
    const int q   = blockIdx.x;
    const int tid = threadIdx.x;
    __shared__ float invn[528];
    __shared__ float vals[528];

    for (int j=tid; j<528; j+=256){
        float s = 0.0f;
        for (int kt=0; kt<SKC; kt++) s += nrmp[kt*528 + j];
        invn[j] = 1.0f/(sqrtf(s) + 1e-8f);
    }
    __syncthreads();
    const float invq = invn[MM + q];
    for (int j=tid; j<528; j+=256){
        float s = 0.0f;
        for (int kt=0; kt<SKC; kt++) s += dotp[((size_t)kt*528 + j)*16 + q];
        vals[j] = s * invn[j] * invq;
    }
    __syncthreads();
    if (tid < 64){
        const int lane = tid;
        for (int kk=0; kk<KNN; kk++){
            float bv = -3.0e38f; int bi = 1<<30;
            for (int j=lane; j<528; j+=64){
                float v2 = vals[j];
                if (v2 > bv || (v2 == bv && j < bi)){ bv = v2; bi = j; }
            }
#pragma unroll
            for (int msk=1; msk<64; msk<<=1){
                float ov = __shfl_xor(bv, msk);
                int   oi = __shfl_xor(bi, msk);
                if (ov > bv || (ov == bv && oi < bi)){ bv = ov; bi = oi; }
            }
            if (lane == 0){
                idx[q*KNN + kk] = bi;
                vals[bi] = -3.0e38f;
            }
        }
    }
}

__global__ __launch_bounds__(256)
void fuse_k(const float* __restrict__ pred, const float* __restrict__ bank,
            const int* __restrict__ idx, float* __restrict__ out){
    int u = blockIdx.x*256 + threadIdx.x;
    int b = u / (PN/4);
    int e = (u - b*(PN/4)) * 4;
    int id[KNN];
#pragma unroll
    for (int k2=0;k2<KNN;k2++) id[k2] = idx[b*KNN + k2];
    float4 pv = *(const float4*)(pred + (size_t)b*PN + e);
    float ax = 0.5f*pv.x, ay = 0.5f*pv.y, az = 0.5f*pv.z, aw = 0.5f*pv.w;
#pragma unroll
    for (int k2=0;k2<KNN;k2++){
        const float* rp = (id[k2] < MM) ? (bank + (size_t)id[k2]*PN)
                                        : (pred + (size_t)(id[k2]-MM)*PN);
        float4 rv = *(const float4*)(rp + e);
        ax = fmaf(0.05f, rv.x, ax); ay = fmaf(0.05f, rv.y, ay);
        az = fmaf(0.05f, rv.z, az); aw = fmaf(0.05f, rv.w, aw);
    }
    float4 ov; ov.x=ax; ov.y=ay; ov.z=az; ov.w=aw;
    *(float4*)(out + (size_t)b*PN + e) = ov;
}

// ---------------------------------------------------------------------------
extern "C" void kernel_launch(void* const* d_in, const int* in_sizes, int n_in,
                              void* d_out, int out_size, void* d_ws, size_t ws_size,
                              hipStream_t stream)
{
    (void)in_sizes; (void)n_in; (void)out_size; (void)ws_size;
    const float* x_enc  = (const float*)d_in[0];
    const float* x_mark = (const float*)d_in[1];
    const float* W_emb  = (const float*)d_in[4];
    const float* b_emb  = (const float*)d_in[5];
    const float* Wq  = (const float*)d_in[6];
    const float* Wk  = (const float*)d_in[7];
    const float* Wv  = (const float*)d_in[8];
    const float* Wo  = (const float*)d_in[9];
    const float* bq  = (const float*)d_in[10];
    const float* bk  = (const float*)d_in[11];
    const float* bv_ = (const float*)d_in[12];
    const float* bo  = (const float*)d_in[13];
    const float* ln1w = (const float*)d_in[14];
    const float* ln1b = (const float*)d_in[15];
    const float* ln2w = (const float*)d_in[16];
    const float* ln2b = (const float*)d_in[17];
    const float* Wff1 = (const float*)d_in[18];
    const float* bff1 = (const float*)d_in[19];
    const float* Wff2 = (const float*)d_in[20];
    const float* bff2 = (const float*)d_in[21];
    const float* lnfw = (const float*)d_in[22];
    const float* lnfb = (const float*)d_in[23];
    const float* Wproj = (const float*)d_in[24];
    const float* bproj = (const float*)d_in[25];
    const float* bank  = (const float*)d_in[26];
    float* out = (float*)d_out;

    char* pp = (char*)d_ws;
    auto a16 = [&](size_t elems)->uint16_t*{ uint16_t* r=(uint16_t*)pp; pp += ((elems*2 + 255)/256)*256; return r; };
    auto af  = [&](size_t elems)->float*  { float* r=(float*)pp;  pp += ((elems*4 + 255)/256)*256; return r; };

    uint16_t* wembT = a16(262144);
    uint16_t* wqkvT = a16((size_t)2*1536*512);
    uint16_t* woT   = a16((size_t)2*262144);
    uint16_t* wff1T = a16((size_t)2*2048*512);
    uint16_t* wff2T = a16((size_t)2*512*2048);
    uint16_t* wprjT = a16(172032);
    float*    bqkv  = af(3072);
    uint16_t* hb    = a16((size_t)BT*512);    // fp16 residual stream
    uint16_t* tok   = a16((size_t)BT*512);
    uint16_t* og16  = a16((size_t)BT*512);    // fp16 sublayer outputs
    uint16_t* qsh   = a16((size_t)128*TT*64);
    uint16_t* ksh   = a16((size_t)128*TT*64);
    uint16_t* vsh   = a16((size_t)128*64*VSTR + 4096);
    uint16_t* t1b   = a16((size_t)BT*512);
    uint16_t* midb  = qsh;   // FF1 out aliases qsh..t1b (all dead at FF1 time)
    float*    pred  = af((size_t)BB*PN);
    float*    dotp  = af((size_t)SKC*528*16);
    float*    nrmp  = af(SKC*528);
    int*      idxp  = (int*)af(256);

    dim3 blk(256);

    tok_k<<<dim3(17,16,BB), blk, 0, stream>>>(x_enc, x_mark, tok);

    WtrTab tab;
    tab.d[0] = { W_emb, wembT, 512, 512, 16, 16, 262144, 0 };
    tab.d[1] = { Wq, wqkvT,          512, 512, 16, 16, 786432, 256 };
    tab.d[2] = { Wk, wqkvT + 262144, 512, 512, 16, 16, 786432, 768 };
    tab.d[3] = { Wv, wqkvT + 524288, 512, 512, 16, 16, 786432, 1280 };
    tab.d[4] = { Wo, woT, 512, 512, 16, 16, 262144, 1792 };
    tab.d[5] = { Wff1, wff1T, 512, 2048, 64, 16, 1048576, 2304 };
    tab.d[6] = { Wff2, wff2T, 2048, 512, 16, 64, 1048576, 4352 };
    tab.d[7] = { Wproj, wprjT, 512, 336, 11, 16, 172032, 6400 };
    wtrall_k<<<dim3(6576), blk, 0, stream>>>(tab);
    catb_k<<<dim3(12), blk, 0, stream>>>(bq, bk, bv_, bqkv);

    // embedding -> fp16 residual stream hb
    ggemm<64, EPI_H16><<<dim3(8,65), blk, 0, stream>>>(
        tok, wembT, b_emb, nullptr, hb, nullptr, nullptr, BT, 512, 512);

    for (int i=0;i<2;i++){
        ggemm<128, EPI_QKV><<<dim3(12,65), blk, 0, stream>>>(
            hb, wqkvT + (size_t)i*786432, bqkv + i*1536,
            nullptr, qsh, ksh, vsh, BT, 1536, 512);
        attnm_k<<<dim3(9,HH,BB), blk, 0, stream>>>(qsh, ksh, vsh, t1b);
        ggemm<64, EPI_H16><<<dim3(8,65), blk, 0, stream>>>(
            t1b, woT + (size_t)i*262144, bo + i*512, nullptr, og16,
            nullptr, nullptr, BT, 512, 512);
        ln_k<<<dim3(BT/4), blk, 0, stream>>>(hb, og16, ln1w + i*512, ln1b + i*512, hb);
        ggemm<128, EPI_GELU|EPI_H16><<<dim3(16,65), blk, 0, stream>>>(
            hb, wff1T + (size_t)i*1048576, bff1 + i*DFFN,
            nullptr, midb, nullptr, nullptr, BT, DFFN, 512);
        ggemm<64, EPI_H16><<<dim3(8,65), blk, 0, stream>>>(
            midb, wff2T + (size_t)i*1048576, bff2 + i*512, nullptr, og16,
            nullptr, nullptr, BT, 512, DFFN);
        ln_k<<<dim3(BT/4), blk, 0, stream>>>(hb, og16, ln2w + i*512, ln2b + i*512, hb);
    }

    ln_k<<<dim3(BT/4), blk, 0, stream>>>(hb, nullptr, lnfw, lnfb, hb);

    ggemm<64, EPI_PREDT><<<dim3(6,65), blk, 0, stream>>>(
        hb, wprjT, bproj, pred, nullptr, nullptr, nullptr, BT, PP, 512);

    sims_k<<<dim3(33,SKC), blk, 0, stream>>>(pred, bank, dotp, nrmp);
    simstail_k<<<dim3(BB), blk, 0, stream>>>(dotp, nrmp, idxp);
    fuse_k<<<dim3((BB*PN/4)/256), blk, 0, stream>>>(pred, bank, idxp, out);
}